// Round 1
// baseline (1147.204 us; speedup 1.0000x reference)
//
#include <hip/hip_runtime.h>
#include <cstdint>
#include <cstddef>

#define B_ROWS 16384
#define EMB_LEN 16384
#define K_DIM 128
#define JSPLIT 2
#define JLEN (EMB_LEN / JSPLIT)   // 8192
#define ROWS_PER_BLOCK 64
#define JT 128                    // j-tile
#define KC 32                     // k chunk

// ---------------------------------------------------------------------------
// Kernel 1: zf + C per row.
// zf[b, c*8 + d*4 + h*2 + w'] = 0.5*z[b,c,h,2w'] + 0.5*z[b,c,h,2w'+1]
// C[b] = sum_i zf[b,i]^2  (fp32, any order: offset is multiple of the local ulp)
// ---------------------------------------------------------------------------
__global__ void zf_kernel(const float* __restrict__ z,
                          float* __restrict__ zf, float* __restrict__ Cb) {
    int b = blockIdx.x;
    int i = threadIdx.x;                 // 0..127
    int c = i >> 3, h = (i >> 1) & 1, wp = i & 1;
    const float* zr = z + (size_t)b * 128 + c * 8 + h * 4 + wp * 2;
    float v = 0.5f * zr[0] + 0.5f * zr[1];
    zf[(size_t)b * 128 + i] = v;
    float s = v * v;
    for (int o = 32; o; o >>= 1) s += __shfl_down(s, o, 64);
    __shared__ float sm[2];
    if ((threadIdx.x & 63) == 0) sm[threadIdx.x >> 6] = s;
    __syncthreads();
    if (threadIdx.x == 0) Cb[b] = sm[0] + sm[1];
}

// ---------------------------------------------------------------------------
// Kernel 2: per-(row-block, j-split) argmin of d = C - 2*dot(zf, e_j).
// Sequential ascending-k fp32 FMA chain per (r,j) to mimic BLAS sgemm rounding.
// ---------------------------------------------------------------------------
__launch_bounds__(512)
__global__ void argmin_kernel(const float* __restrict__ zf,
                              const float* __restrict__ Cb,
                              const float* __restrict__ emb,
                              float* __restrict__ cand_d,
                              int* __restrict__ cand_j) {
    __shared__ float zfs[K_DIM][ROWS_PER_BLOCK];   // [k][r] 32 KB, resident
    __shared__ float es[KC][JT];                   // [k][j] 16 KB, staged

    int rb = blockIdx.x & 255;        // 256 row-blocks
    int sp = blockIdx.x >> 8;         // split 0..1
    int rbase = rb * ROWS_PER_BLOCK;
    int jbase0 = sp * JLEN;
    int tid = threadIdx.x;
    int tj = tid & 31, tr = tid >> 5; // tr 0..15
    int tj4 = tj << 2, tr4 = tr << 2;

    // stage zf tile transposed: zfs[k][r]
    {
        int r0 = tid >> 5;            // 0..15
        int k4 = (tid & 31) << 2;     // 0..124
        for (int rr = 0; rr < ROWS_PER_BLOCK; rr += 16) {
            const float4 v = *(const float4*)(zf + (size_t)(rbase + r0 + rr) * 128 + k4);
            zfs[k4 + 0][r0 + rr] = v.x;
            zfs[k4 + 1][r0 + rr] = v.y;
            zfs[k4 + 2][r0 + rr] = v.z;
            zfs[k4 + 3][r0 + rr] = v.w;
        }
    }
    float cb[4];
#pragma unroll
    for (int i = 0; i < 4; ++i) cb[i] = Cb[rbase + tr4 + i];

    float bestd[4];
    int bestj[4];
#pragma unroll
    for (int i = 0; i < 4; ++i) { bestd[i] = 3.4e38f; bestj[i] = 0; }

    for (int jt = 0; jt < JLEN; jt += JT) {
        float acc[4][4];
#pragma unroll
        for (int ri = 0; ri < 4; ++ri)
#pragma unroll
            for (int ji = 0; ji < 4; ++ji) acc[ri][ji] = 0.0f;

        for (int kc = 0; kc < K_DIM; kc += KC) {
            __syncthreads();   // protect es reuse (also orders zfs staging on 1st iter)
            {
                int j0 = tid >> 3;            // 0..63
                int kk4 = (tid & 7) << 2;     // 0..28
                const float* ebase = emb + (size_t)(jbase0 + jt) * 128 + kc;
                for (int jj = 0; jj < JT; jj += 64) {
                    const float4 v = *(const float4*)(ebase + (size_t)(j0 + jj) * 128 + kk4);
                    es[kk4 + 0][j0 + jj] = v.x;
                    es[kk4 + 1][j0 + jj] = v.y;
                    es[kk4 + 2][j0 + jj] = v.z;
                    es[kk4 + 3][j0 + jj] = v.w;
                }
            }
            __syncthreads();
#pragma unroll
            for (int k = 0; k < KC; ++k) {
                const float4 av = *(const float4*)(&zfs[kc + k][tr4]);
                const float4 bv = *(const float4*)(&es[k][tj4]);
                float a[4] = {av.x, av.y, av.z, av.w};
                float bb[4] = {bv.x, bv.y, bv.z, bv.w};
#pragma unroll
                for (int ri = 0; ri < 4; ++ri)
#pragma unroll
                    for (int ji = 0; ji < 4; ++ji)
                        acc[ri][ji] = fmaf(a[ri], bb[ji], acc[ri][ji]);
            }
        }
        // d = C - 2*g; strict < keeps earliest (smallest) j
#pragma unroll
        for (int ji = 0; ji < 4; ++ji) {
            int j = jbase0 + jt + tj4 + ji;
#pragma unroll
            for (int ri = 0; ri < 4; ++ri) {
                float dv = cb[ri] - 2.0f * acc[ri][ji];
                if (dv < bestd[ri]) { bestd[ri] = dv; bestj[ri] = j; }
            }
        }
    }

    // cross-tj reduce (lexicographic (d, j) min), reuse zfs memory
    __syncthreads();
    float* cdm = (float*)zfs;                                  // [64][32] 8 KB
    int* cjm = (int*)((char*)zfs + ROWS_PER_BLOCK * 32 * 4);   // [64][32] 8 KB
#pragma unroll
    for (int ri = 0; ri < 4; ++ri) {
        int r = tr4 + ri;
        cdm[r * 32 + tj] = bestd[ri];
        cjm[r * 32 + tj] = bestj[ri];
    }
    __syncthreads();
    if (tid < ROWS_PER_BLOCK) {
        float bd = cdm[tid * 32];
        int bj = cjm[tid * 32];
        for (int t = 1; t < 32; ++t) {
            float d2 = cdm[tid * 32 + t];
            int j2 = cjm[tid * 32 + t];
            if (d2 < bd || (d2 == bd && j2 < bj)) { bd = d2; bj = j2; }
        }
        cand_d[sp * B_ROWS + rbase + tid] = bd;
        cand_j[sp * B_ROWS + rbase + tid] = bj;
    }
}

// ---------------------------------------------------------------------------
// Kernel 3: merge splits (ascending split => smaller j wins ties via strict <)
// ---------------------------------------------------------------------------
__global__ void merge_kernel(const float* __restrict__ cand_d,
                             const int* __restrict__ cand_j,
                             int* __restrict__ idxw,
                             float* __restrict__ out_idx) {
    int b = blockIdx.x * 256 + threadIdx.x;
    float bd = cand_d[b];
    int bj = cand_j[b];
#pragma unroll
    for (int s = 1; s < JSPLIT; ++s) {
        float d = cand_d[s * B_ROWS + b];
        int j = cand_j[s * B_ROWS + b];
        if (d < bd) { bd = d; bj = j; }
    }
    idxw[b] = bj;
    out_idx[b] = (float)bj;
}

// ---------------------------------------------------------------------------
// Kernel 4: z_q_out (transposed) + moment sums for loss
// ---------------------------------------------------------------------------
__global__ void output_kernel(const float* __restrict__ z,
                              const float* __restrict__ emb,
                              const int* __restrict__ idxw,
                              float* __restrict__ out,
                              double* __restrict__ accs) {
    int stride = gridDim.x * blockDim.x;
    double s[6] = {0, 0, 0, 0, 0, 0};
    for (int n = blockIdx.x * blockDim.x + threadIdx.x; n < B_ROWS * 128; n += stride) {
        int b = n >> 7, i = n & 127;
        int c = i >> 3, h = (i >> 2) & 1, w = i & 3;   // i = c*8 + h*4 + w
        float zv = z[n];
        float qv = emb[(size_t)idxw[b] * 128 + i];
        float diff = qv - zv;                          // z_q - z (fp32, as ref)
        out[(size_t)((b * 4 + w) * 16 + c) * 2 + h] = zv + diff;
        s[0] += (double)qv;
        s[1] += (double)zv;
        s[2] += (double)qv * qv;
        s[3] += (double)zv * zv;
        s[4] += (double)qv * zv;
        s[5] += (double)diff * diff;
    }
    // reduce 6 doubles across block
    int lane = threadIdx.x & 63, wv = threadIdx.x >> 6;
#pragma unroll
    for (int q = 0; q < 6; ++q)
        for (int o = 32; o; o >>= 1) s[q] += __shfl_down(s[q], o, 64);
    __shared__ double sm[6][4];
    if (lane == 0)
#pragma unroll
        for (int q = 0; q < 6; ++q) sm[q][wv] = s[q];
    __syncthreads();
    if (threadIdx.x == 0) {
#pragma unroll
        for (int q = 0; q < 6; ++q)
            atomicAdd(&accs[q], sm[q][0] + sm[q][1] + sm[q][2] + sm[q][3]);
    }
}

// ---------------------------------------------------------------------------
// Kernel 5: per-column L1 of emb (for reg term)
// ---------------------------------------------------------------------------
__global__ void colsum_kernel(const float* __restrict__ emb, float* __restrict__ colsum) {
    int j = blockIdx.x;   // 0..127
    double s = 0;
    for (int i = threadIdx.x; i < EMB_LEN; i += blockDim.x)
        s += (double)fabsf(emb[(size_t)i * 128 + j]);
    int lane = threadIdx.x & 63, wv = threadIdx.x >> 6;
    for (int o = 32; o; o >>= 1) s += __shfl_down(s, o, 64);
    __shared__ double sm[4];
    if (lane == 0) sm[wv] = s;
    __syncthreads();
    if (threadIdx.x == 0) colsum[j] = (float)(sm[0] + sm[1] + sm[2] + sm[3]);
}

// ---------------------------------------------------------------------------
// Kernel 6: final loss
// ---------------------------------------------------------------------------
__global__ void loss_kernel(const double* __restrict__ accs,
                            const float* __restrict__ colsum,
                            float* __restrict__ out_loss) {
    __shared__ float sm[128];
    int tid = threadIdx.x;
    sm[tid] = colsum[tid];
    __syncthreads();
    for (int s = 64; s; s >>= 1) {
        if (tid < s) sm[tid] = fmaxf(sm[tid], sm[tid + s]);
        __syncthreads();
    }
    if (tid == 0) {
        double n = (double)B_ROWS * 128.0;
        double m = accs[5] / n;                   // mean((z_q - z)^2)
        double commit = 0.25 * m + m;
        double Sx = accs[0], Sy = accs[1], Sxx = accs[2], Syy = accs[3], Sxy = accs[4];
        double cov = Sxy - Sx * Sy / n;
        double vx = Sxx - Sx * Sx / n;
        double vy = Syy - Sy * Sy / n;
        double pearson = 0.5 + 0.5 * cov / (sqrt(vx) * sqrt(vy));
        double reg = 0.01 * (double)sm[0];
        out_loss[0] = (float)(commit + pearson + reg);
    }
}

// ---------------------------------------------------------------------------
extern "C" void kernel_launch(void* const* d_in, const int* in_sizes, int n_in,
                              void* d_out, int out_size, void* d_ws, size_t ws_size,
                              hipStream_t stream) {
    const float* z = (const float*)d_in[0];      // 16384*16*2*4
    const float* emb = (const float*)d_in[1];    // 16384*128
    float* out = (float*)d_out;                  // 2097152 (z_q_out) + 1 (loss) + 16384 (idx)

    float* zf = (float*)d_ws;                    // 2097152 floats
    float* Cb = zf + 2097152;                    // 16384
    float* cand_d = Cb + 16384;                  // JSPLIT*16384
    int* cand_j = (int*)(cand_d + JSPLIT * B_ROWS);
    int* idxw = cand_j + JSPLIT * B_ROWS;        // 16384
    double* accs = (double*)(idxw + 16384);      // 8 doubles (byte offset divisible by 8)
    float* colsum = (float*)(accs + 8);          // 128

    hipMemsetAsync(accs, 0, 8 * sizeof(double), stream);

    zf_kernel<<<B_ROWS, 128, 0, stream>>>(z, zf, Cb);
    argmin_kernel<<<256 * JSPLIT, 512, 0, stream>>>(zf, Cb, emb, cand_d, cand_j);
    merge_kernel<<<B_ROWS / 256, 256, 0, stream>>>(cand_d, cand_j, idxw, out + 2097153);
    output_kernel<<<1024, 256, 0, stream>>>(z, emb, idxw, out, accs);
    colsum_kernel<<<128, 256, 0, stream>>>(emb, colsum);
    loss_kernel<<<1, 128, 0, stream>>>(accs, colsum, out + 2097152);
}